// Round 14
// baseline (102.453 us; speedup 1.0000x reference)
//
#include <hip/hip_runtime.h>

constexpr int H = 192, W = 192, D = 192;
constexpr int BH = 16, BW = 16, BZ = 16;   // output tile per block
constexpr int TY = 23, TX = 23, TZ = 24;   // slab: x/y halo -3..+19, z halo -4..+19
constexpr int TILE_DATA = TY * TX * TZ;    // 12696 dwords = 50.8 KB data
constexpr int LDS_DWORDS = 3264 * 4;       // 51 chunk-instrs -> 51 KB, 3 blocks/CU
constexpr int BMAX = TILE_DATA - 2;        // full path reads only tile[b], tile[b+1]
constexpr int NB1 = 40;                    // batch1: instrs 0..39 (5/wave, uniform)
// batch1 covers chunks 0..2559 -> all rows with ly<=17 fully staged.
// batch2: instrs 40..50 (waves 0-7 issue #40+wv; waves 0-2 also #48+wv).

// Exact reference semantics for one voxel, all-global (fallback path).
__device__ __forceinline__ float ref_voxel(const float* __restrict__ I,
                                           float x, float y, float zf)
{
    int fx = (int)floorf(x), fy = (int)floorf(y), fz = (int)floorf(zf);
    int x0 = min(max(fx, 0), W + 1), x1 = min(max(fx + 1, 0), W + 1);
    int y0 = min(max(fy, 0), H + 1), y1 = min(max(fy + 1, 0), H + 1);
    int zp0 = min(max(fz, 0), D + 1), zp1 = min(max(fz + 1, 0), D + 1);
    float dx = (float)x1 - x, dy = (float)y1 - y, dz = (float)zp1 - zf;
    int xi0 = x0 - 1, xi1 = x1 - 1, yi0 = y0 - 1, yi1 = y1 - 1;
    int zi = zp0 - 1, zj = zp1 - 1;
    float ax0 = ((unsigned)xi0 < (unsigned)W) ? dx       : 0.f;
    float ax1 = ((unsigned)xi1 < (unsigned)W) ? 1.f - dx : 0.f;
    float ay0 = ((unsigned)yi0 < (unsigned)H) ? dy       : 0.f;
    float ay1 = ((unsigned)yi1 < (unsigned)H) ? 1.f - dy : 0.f;
    float az0 = ((unsigned)zi  < (unsigned)D) ? dz       : 0.f;
    float az1 = ((unsigned)zj  < (unsigned)D) ? 1.f - dz : 0.f;
    int xc0 = min(max(xi0, 0), W - 1), xc1 = min(max(xi1, 0), W - 1);
    int yc0 = min(max(yi0, 0), H - 1), yc1 = min(max(yi1, 0), H - 1);
    int zc0 = min(max(zi, 0), D - 1),  zc1 = min(max(zj, 0), D - 1);
    const float* r00 = I + (yc0 * W + xc0) * D;
    const float* r01 = I + (yc0 * W + xc1) * D;
    const float* r10 = I + (yc1 * W + xc0) * D;
    const float* r11 = I + (yc1 * W + xc1) * D;
    float s00 = az0 * r00[zc0] + az1 * r00[zc1];
    float s01 = az0 * r01[zc0] + az1 * r01[zc1];
    float s10 = az0 * r10[zc0] + az1 * r10[zc1];
    float s11 = az0 * r11[zc0] + az1 * r11[zc1];
    return ay0 * (ax0 * s00 + ax1 * s01) + ay1 * (ax0 * s10 + ax1 * s11);
}

// One staging chunk-instruction: 64 lanes, 16B each, clamped source, linear dest.
__device__ __forceinline__ void stage_instr(const float* __restrict__ I, float* tile,
                                            unsigned i, unsigned lane,
                                            int xg0, int yg0, int zg0)
{
    unsigned c = i * 64u + lane;
    unsigned row = c / 6u;             // 6 chunks per row (TZ=24)
    unsigned s = c - row * 6u;
    unsigned ry = row / 23u;
    unsigned rx = row - ry * 23u;
    int gy = min(max(yg0 + (int)min(ry, 22u), 0), H - 1);
    int gx = min(max(xg0 + (int)rx, 0), W - 1);
    int zs = min(max(zg0 + (int)(s * 4u), 0), D - 4);
    const float* src = I + ((gy * W + gx) * D + zs);
    __builtin_amdgcn_global_load_lds(
        (const __attribute__((address_space(1))) void*)src,
        (__attribute__((address_space(3))) void*)(tile + i * 256u),
        16, 0, 0);
}

__global__ __launch_bounds__(512, 6) void st_tile(
    const float* __restrict__ I,
    const float* __restrict__ dxt,
    const float* __restrict__ dyt,
    const float* __restrict__ dzt,
    float* __restrict__ out)
{
    __shared__ float tile[LDS_DWORDS];   // 51 KB -> 3 blocks/CU

    const int tid = threadIdx.x;
    const int bx = blockIdx.x, by = blockIdx.y, bz = blockIdx.z;
    const int w0 = bx * BW, h0 = by * BH, z0 = bz * BZ;
    const int xg0 = w0 - 3, yg0 = h0 - 3, zg0 = z0 - 4;

    const unsigned wv = tid >> 6, lane = tid & 63;
    const int zq = tid & 3, wloc = (tid >> 2) & 15, hl0 = tid >> 6;   // hl0 in [0,7]
    const int wg = w0 + wloc;

    // ---- batch1: uniform 5 instrs/wave, covers all rows half0 can touch ----
    #pragma unroll
    for (unsigned t = 0; t < 5; ++t)
        stage_instr(I, tile, wv + 8u * t, lane, xg0, yg0, zg0);
    __builtin_amdgcn_sched_barrier(0);

    // ---- disp loads, half0 ----
    const int t40 = ((h0 + hl0) * W + wg) * (D / 4) + (z0 >> 2) + zq;
    float4 vx0 = reinterpret_cast<const float4*>(dxt)[t40];
    float4 vy0 = reinterpret_cast<const float4*>(dyt)[t40];
    float4 vz0 = reinterpret_cast<const float4*>(dzt)[t40];
    __builtin_amdgcn_sched_barrier(0);

    // ---- batch2: remaining rows (waves 0-7: instr 40+wv; waves 0-2: +instr 48+wv) ----
    stage_instr(I, tile, 40u + wv, lane, xg0, yg0, zg0);
    if (wv < 3) stage_instr(I, tile, 48u + wv, lane, xg0, yg0, zg0);
    __builtin_amdgcn_sched_barrier(0);

    // ---- disp loads, half1 ----
    const int t41 = ((h0 + 8 + hl0) * W + wg) * (D / 4) + (z0 >> 2) + zq;
    float4 vx1 = reinterpret_cast<const float4*>(dxt)[t41];
    float4 vy1 = reinterpret_cast<const float4*>(dyt)[t41];
    float4 vz1 = reinterpret_cast<const float4*>(dzt)[t41];
    __builtin_amdgcn_sched_barrier(0);

    // wait: allow newest 4 (own batch2 tail + disp1); forces batch1 + disp0 complete
    // for every wave regardless of its batch2 count (1 or 2).
    asm volatile("s_waitcnt vmcnt(4)" ::: "memory");
    __builtin_amdgcn_s_barrier();
    __builtin_amdgcn_sched_barrier(0);

    // block-uniform fast-path bounds
    const int lox = max(0, -xg0), hix = min(TX - 2, 190 - xg0);
    const int loy = max(0, -yg0), hiy = min(TY - 2, 190 - yg0);
    const int loz = max(0, -zg0), hiz = min(TZ - 2, 190 - zg0);

    #pragma unroll
    for (int half = 0; half < 2; ++half) {
        const int hl = hl0 + half * 8;
        const int hg = h0 + hl;
        float4 vx = half ? vx1 : vx0;
        float4 vy = half ? vy1 : vy0;
        float4 vz = half ? vz1 : vz0;
        float rxj[4] = {vx.x, vx.y, vx.z, vx.w};
        float ryj[4] = {vy.x, vy.y, vy.z, vy.w};
        float rzj[4] = {vz.x, vz.y, vz.z, vz.w};
        float ro[4];

        // ---- phase A: local coords + fast flags ----
        int   lxa[4], lya[4], lza[4];
        float txa[4], tya[4], tza[4];
        bool  fa[4];
        #pragma unroll
        for (int j = 0; j < 4; ++j) {
            float xl = rxj[j] + (float)(wloc + 3);
            float yl = ryj[j] + (float)(hl + 3);
            float zl = rzj[j] + (float)(zq * 4 + j + 4);
            float fxf = floorf(xl), fyf = floorf(yl), fzf = floorf(zl);
            lxa[j] = (int)fxf; lya[j] = (int)fyf; lza[j] = (int)fzf;
            txa[j] = xl - fxf; tya[j] = yl - fyf; tza[j] = zl - fzf;
            fa[j] = ((unsigned)(lxa[j] - lox) <= (unsigned)(hix - lox))
                  & ((unsigned)(lya[j] - loy) <= (unsigned)(hiy - loy))
                  & ((unsigned)(lza[j] - loz) <= (unsigned)(hiz - loz));
        }

        if (__builtin_expect(__all(fa[0] & fa[1] & fa[2] & fa[3]), 1)) {
            // ---- fast path: no clamps, plain frac weights (R8/R9/R11-verified) ----
            // fa bounds guarantee max read b + TX*TZ + TZ + 1 <= TILE_DATA - 1.
            #pragma unroll
            for (int j = 0; j < 4; ++j) {
                int b = (lya[j] * TX + lxa[j]) * TZ + lza[j];
                float a0 = tile[b],                a1 = tile[b + 1];
                float b0 = tile[b + TZ],           b1 = tile[b + TZ + 1];
                float c0 = tile[b + TX * TZ],      c1 = tile[b + TX * TZ + 1];
                float d0 = tile[b + TX * TZ + TZ], d1 = tile[b + TX * TZ + TZ + 1];
                float wz0 = 1.f - tza[j], wz1 = tza[j];
                float wx0 = 1.f - txa[j], wx1 = txa[j];
                float wy0 = 1.f - tya[j], wy1 = tya[j];
                float s00 = wz0 * a0 + wz1 * a1;
                float s01 = wz0 * b0 + wz1 * b1;
                float s10 = wz0 * c0 + wz1 * c1;
                float s11 = wz0 * d0 + wz1 * d1;
                ro[j] = wy0 * (wx0 * s00 + wx1 * s01) + wy1 * (wx0 * s10 + wx1 * s11);
            }
        } else {
            // ---- full path: reference clamp semantics (R6..R11-verified) ----
            #pragma unroll
            for (int j = 0; j < 4; ++j) {
                const int zv = z0 + zq * 4 + j;
                float x  = rxj[j] + (float)(wg + 1);
                float y  = ryj[j] + (float)(hg + 1);
                float zf = rzj[j] + (float)(zv + 1);

                int fx = (int)floorf(x), fy = (int)floorf(y), fz = (int)floorf(zf);
                int x0 = min(max(fx, 0), W + 1), x1 = min(max(fx + 1, 0), W + 1);
                int y0 = min(max(fy, 0), H + 1), y1 = min(max(fy + 1, 0), H + 1);
                int zp0 = min(max(fz, 0), D + 1), zp1 = min(max(fz + 1, 0), D + 1);

                float dx = (float)x1 - x, dy = (float)y1 - y, dz = (float)zp1 - zf;

                int xi0 = x0 - 1, xi1 = x1 - 1, yi0 = y0 - 1, yi1 = y1 - 1;
                int zi = zp0 - 1, zj2 = zp1 - 1;

                float ax0 = ((unsigned)xi0 < (unsigned)W) ? dx       : 0.f;
                float ax1 = ((unsigned)xi1 < (unsigned)W) ? 1.f - dx : 0.f;
                float ay0 = ((unsigned)yi0 < (unsigned)H) ? dy       : 0.f;
                float ay1 = ((unsigned)yi1 < (unsigned)H) ? 1.f - dy : 0.f;
                float az0 = ((unsigned)zi  < (unsigned)D) ? dz       : 0.f;
                float az1 = ((unsigned)zj2 < (unsigned)D) ? 1.f - dz : 0.f;

                int xc0 = min(max(xi0, 0), W - 1), xc1 = min(max(xi1, 0), W - 1);
                int yc0 = min(max(yi0, 0), H - 1), yc1 = min(max(yi1, 0), H - 1);
                int zc  = min(max(zi, 0), D - 2);

                bool zlo = (zi <= D - 2);
                bool zhi = (zi >= 0);

                int lx0 = xc0 - xg0, lx1 = xc1 - xg0;
                int ly0 = yc0 - yg0, ly1 = yc1 - yg0;
                int lz  = zc - zg0;

                bool ok = ((unsigned)lx0 <= (unsigned)(TX - 1))
                        & ((unsigned)lx1 <= (unsigned)(TX - 1))
                        & ((unsigned)ly0 <= (unsigned)(TY - 1))
                        & ((unsigned)ly1 <= (unsigned)(TY - 1))
                        & ((unsigned)lz  <= (unsigned)(TZ - 2));

                int b00 = min(max((ly0 * TX + lx0) * TZ + lz, 0), BMAX);
                int b01 = min(max((ly0 * TX + lx1) * TZ + lz, 0), BMAX);
                int b10 = min(max((ly1 * TX + lx0) * TZ + lz, 0), BMAX);
                int b11 = min(max((ly1 * TX + lx1) * TZ + lz, 0), BMAX);

                float a0 = tile[b00], a1 = tile[b00 + 1];
                float b0 = tile[b01], b1 = tile[b01 + 1];
                float c0 = tile[b10], c1 = tile[b10 + 1];
                float d0 = tile[b11], d1 = tile[b11 + 1];

                float v000 = zlo ? a0 : a1, v001 = zhi ? a1 : a0;
                float v010 = zlo ? b0 : b1, v011 = zhi ? b1 : b0;
                float v100 = zlo ? c0 : c1, v101 = zhi ? c1 : c0;
                float v110 = zlo ? d0 : d1, v111 = zhi ? d1 : d0;
                float s00 = az0 * v000 + az1 * v001;
                float s01 = az0 * v010 + az1 * v011;
                float s10 = az0 * v100 + az1 * v101;
                float s11 = az0 * v110 + az1 * v111;
                float r = ay0 * (ax0 * s00 + ax1 * s01)
                        + ay1 * (ax0 * s10 + ax1 * s11);

                ro[j] = __builtin_expect(ok, 1) ? r : ref_voxel(I, x, y, zf);
            }
        }

        reinterpret_cast<float4*>(out)[half ? t41 : t40] =
            make_float4(ro[0], ro[1], ro[2], ro[3]);

        if (half == 0) {
            // allow only the half0 store outstanding: forces batch2 + disp1 done
            asm volatile("s_waitcnt vmcnt(1)" ::: "memory");
            __builtin_amdgcn_s_barrier();
            __builtin_amdgcn_sched_barrier(0);
        }
    }
}

extern "C" void kernel_launch(void* const* d_in, const int* in_sizes, int n_in,
                              void* d_out, int out_size, void* d_ws, size_t ws_size,
                              hipStream_t stream) {
    const float* I   = (const float*)d_in[0];
    const float* dxt = (const float*)d_in[1];
    const float* dyt = (const float*)d_in[2];
    const float* dzt = (const float*)d_in[3];
    float* out = (float*)d_out;

    dim3 grid(W / BW, H / BH, D / BZ);   // 12 x 12 x 12 = 1728 blocks
    hipLaunchKernelGGL(st_tile, grid, dim3(512), 0, stream,
                       I, dxt, dyt, dzt, out);
}